// Round 6
// baseline (218.859 us; speedup 1.0000x reference)
//
#include <hip/hip_runtime.h>
#include <math.h>

#define B_TOT 512
#define S_LEN 256
#define D_IN  64
#define HDIM  128

typedef float v2f __attribute__((ext_vector_type(2)));

// ---- fast scalar ops (raw HW instructions; ~1-2 ulp, threshold is 1.5e-2) ----
__device__ __forceinline__ float rcp_f(float x) { return __builtin_amdgcn_rcpf(x); }
__device__ __forceinline__ float rsq_f(float x) { return __builtin_amdgcn_rsqf(x); }

__device__ __forceinline__ v2f fma2(v2f a, v2f b, v2f c) { return __builtin_elementwise_fma(a, b, c); }
__device__ __forceinline__ v2f splat2(float s) { v2f r = {s, s}; return r; }

// plain tanh (used once, for tanh(c))
__device__ __forceinline__ v2f tanh2(v2f s) {
    v2f t = s + s;
    v2f e = { __expf(t.x), __expf(t.y) };
    v2f ONE = {1.f, 1.f};
    v2f d = e + ONE;
    v2f r = { rcp_f(d.x), rcp_f(d.y) };
    v2f NTWO = {-2.f, -2.f};
    return fma2(r, NTWO, ONE);   // 1 - 2r
}

// quad broadcast: every lane gets quad-lane Q's value (DPP, full-rate VALU)
template<int Q>
__device__ __forceinline__ float quad_bcast(float v) {
    constexpr int ctrl = Q | (Q << 2) | (Q << 4) | (Q << 6);
    int t = __builtin_amdgcn_update_dpp(0, __float_as_int(v), ctrl, 0xF, 0xF, true);
    return __int_as_float(t);
}

// ---------------------------------------------------------------------------
// Fused 4-value 64-lane all-reduce, one asm block, NO LDS.
// After 6 DPP stages lanes 48-63 hold the full total (proven rounds 4-5);
// v_readlane lane 63 -> SGPR: no LDS round-trip, no lgkmcnt wait.
// ---------------------------------------------------------------------------
__device__ __forceinline__ void reduce4(float p0, float p1, float p2, float p3,
                                        float& y0, float& y1, float& y2, float& y3) {
    asm volatile(
        "s_nop 1\n\t"
        "v_add_f32 %0, %0, %0 quad_perm:[1,0,3,2] row_mask:0xf bank_mask:0xf\n\t"
        "v_add_f32 %1, %1, %1 quad_perm:[1,0,3,2] row_mask:0xf bank_mask:0xf\n\t"
        "v_add_f32 %2, %2, %2 quad_perm:[1,0,3,2] row_mask:0xf bank_mask:0xf\n\t"
        "v_add_f32 %3, %3, %3 quad_perm:[1,0,3,2] row_mask:0xf bank_mask:0xf\n\t"
        "v_add_f32 %0, %0, %0 quad_perm:[2,3,0,1] row_mask:0xf bank_mask:0xf\n\t"
        "v_add_f32 %1, %1, %1 quad_perm:[2,3,0,1] row_mask:0xf bank_mask:0xf\n\t"
        "v_add_f32 %2, %2, %2 quad_perm:[2,3,0,1] row_mask:0xf bank_mask:0xf\n\t"
        "v_add_f32 %3, %3, %3 quad_perm:[2,3,0,1] row_mask:0xf bank_mask:0xf\n\t"
        "v_add_f32 %0, %0, %0 row_half_mirror row_mask:0xf bank_mask:0xf\n\t"
        "v_add_f32 %1, %1, %1 row_half_mirror row_mask:0xf bank_mask:0xf\n\t"
        "v_add_f32 %2, %2, %2 row_half_mirror row_mask:0xf bank_mask:0xf\n\t"
        "v_add_f32 %3, %3, %3 row_half_mirror row_mask:0xf bank_mask:0xf\n\t"
        "v_add_f32 %0, %0, %0 row_mirror row_mask:0xf bank_mask:0xf\n\t"
        "v_add_f32 %1, %1, %1 row_mirror row_mask:0xf bank_mask:0xf\n\t"
        "v_add_f32 %2, %2, %2 row_mirror row_mask:0xf bank_mask:0xf\n\t"
        "v_add_f32 %3, %3, %3 row_mirror row_mask:0xf bank_mask:0xf\n\t"
        "v_add_f32 %0, %0, %0 row_bcast:15 row_mask:0xf bank_mask:0xf bound_ctrl:0\n\t"
        "v_add_f32 %1, %1, %1 row_bcast:15 row_mask:0xf bank_mask:0xf bound_ctrl:0\n\t"
        "v_add_f32 %2, %2, %2 row_bcast:15 row_mask:0xf bank_mask:0xf bound_ctrl:0\n\t"
        "v_add_f32 %3, %3, %3 row_bcast:15 row_mask:0xf bank_mask:0xf bound_ctrl:0\n\t"
        "v_add_f32 %0, %0, %0 row_bcast:31 row_mask:0xf bank_mask:0xf bound_ctrl:0\n\t"
        "v_add_f32 %1, %1, %1 row_bcast:31 row_mask:0xf bank_mask:0xf bound_ctrl:0\n\t"
        "v_add_f32 %2, %2, %2 row_bcast:31 row_mask:0xf bank_mask:0xf bound_ctrl:0\n\t"
        "v_add_f32 %3, %3, %3 row_bcast:31 row_mask:0xf bank_mask:0xf bound_ctrl:0\n\t"
        "s_nop 1\n\t"
        "v_readlane_b32 %4, %0, 63\n\t"
        "v_readlane_b32 %5, %1, 63\n\t"
        "v_readlane_b32 %6, %2, 63\n\t"
        "v_readlane_b32 %7, %3, 63"
        : "+v"(p0), "+v"(p1), "+v"(p2), "+v"(p3),
          "=&s"(y0), "=&s"(y1), "=&s"(y2), "=&s"(y3));
}

// ---------------------------------------------------------------------------
// Phase 1: precompute yx[b][t][q] = b_in[q] + sum_d x[b,t,d] * Win[128+d][q].
// ---------------------------------------------------------------------------
__global__ void __launch_bounds__(64, 1) xproj_kernel(
    const float* __restrict__ x,    // (B,S,D)
    const float* __restrict__ Win,  // (192,4)
    const float* __restrict__ bin,  // (4)
    float4* __restrict__ yx)        // (B,S) float4
{
    const int l  = threadIdx.x;
    const int b  = blockIdx.x >> 4;
    const int t0 = (blockIdx.x & 15) << 4;

    const float4 wx = reinterpret_cast<const float4*>(Win)[128 + l];
    const float4 bn = *reinterpret_cast<const float4*>(bin);

    const float* xp = x + ((size_t)b * S_LEN + t0) * D_IN + l;
    float4* yp = yx + (size_t)b * S_LEN + t0;

#pragma unroll 4
    for (int tt = 0; tt < 16; ++tt) {
        float xv = xp[(size_t)tt * D_IN];
        float y0, y1, y2, y3;
        reduce4(xv * wx.x, xv * wx.y, xv * wx.z, xv * wx.w, y0, y1, y2, y3);
        if (l == 0)
            yp[tt] = make_float4(y0 + bn.x, y1 + bn.y, y2 + bn.z, y3 + bn.w);
    }
}

// ---------------------------------------------------------------------------
// Phase 2: serial recurrence. 1 batch per wave (512 waves, 2/CU).
// Lane l owns hidden units 2l, 2l+1. yx row staged in LDS once.
// Bloch block is lane-parallel (lane computes qubit l&3: 2 rsq instrs instead
// of 8) then quad_perm-broadcast back to uniform; sigmoid pairs share one rcp.
// ---------------------------------------------------------------------------
template<bool PRE>
__global__ void __launch_bounds__(64, 1) qlstm_kernel(
    const float* __restrict__ x,    // (B,S,D)
    const float* __restrict__ Win,  // (192,4)
    const float* __restrict__ bin,  // (4)
    const float* __restrict__ Wout, // (4,128)
    const float* __restrict__ bout, // (128)
    const float* __restrict__ wf,   // (1,3,4)
    const float* __restrict__ wi,
    const float* __restrict__ wu,
    const float* __restrict__ wo,
    float* __restrict__ out,        // outs (B,S,128) ++ hT (B,128) ++ cT (B,128)
    const float4* __restrict__ yx)  // (B,S) precomputed x-projection (PRE only)
{
    const int l = threadIdx.x;      // 0..63
    const int b = blockIdx.x;

    __shared__ float4 yxl[S_LEN + 2];   // staged x-projection (+2 pad for prefetch)

    // ---- h-part W_in rows for this lane's two units (packed over q-pairs) ----
    const float4* W4 = reinterpret_cast<const float4*>(Win);
    const float4 r0 = W4[2 * l];
    const float4 r1 = W4[2 * l + 1];
    const v2f wh0a = {r0.x, r0.y}, wh0b = {r0.z, r0.w};
    const v2f wh1a = {r1.x, r1.y}, wh1b = {r1.z, r1.w};

    // x-part (fallback path only): lane owns feature l; bias folded /64
    v2f wxa = {0.f, 0.f}, wxb = {0.f, 0.f}, bna = {0.f, 0.f}, bnb = {0.f, 0.f};
    if (!PRE) {
        const float4 rx = W4[128 + l];
        wxa.x = rx.x; wxa.y = rx.y; wxb.x = rx.z; wxb.y = rx.w;
        const float4 bn = *reinterpret_cast<const float4*>(bin);
        bna.x = bn.x * 0.015625f; bna.y = bn.y * 0.015625f;
        bnb.x = bn.z * 0.015625f; bnb.y = bn.w * 0.015625f;
    } else {
        // stage this batch's yx row into LDS (single wave: no barrier needed)
        const float4* yxg = yx + (size_t)b * S_LEN;
#pragma unroll
        for (int k = 0; k < 4; ++k)
            yxl[(k << 6) + l] = yxg[(k << 6) + l];
    }

    // W_out for units 2l, 2l+1 (packed over the unit pair)
    v2f Wo[4];
#pragma unroll
    for (int q = 0; q < 4; ++q) {
        Wo[q].x = Wout[q * HDIM + 2 * l];
        Wo[q].y = Wout[q * HDIM + 2 * l + 1];
    }
    const v2f bo = {bout[2 * l], bout[2 * l + 1]};

    // measurement coefficients, packed over q-pairs: [g][0]=(q0,q1) [g][1]=(q2,q3)
    v2f UX[4][2], UY[4][2], UZ[4][2];
    {
        const float* wg[4] = {wf, wi, wu, wo};
#pragma unroll
        for (int g = 0; g < 4; ++g) {
#pragma unroll
            for (int p = 0; p < 2; ++p) {
#pragma unroll
                for (int e = 0; e < 2; ++e) {
                    int q = 2 * p + e;
                    float a  = wg[g][q];
                    float be = wg[g][4 + q];
                    float sa = sinf(a),  ca = cosf(a);
                    float sb = sinf(be), cb = cosf(be);
                    UX[g][p][e] = -sb;
                    UY[g][p][e] = cb * sa;
                    UZ[g][p][e] = cb * ca;
                }
            }
        }
    }

    v2f h = {0.f, 0.f}, c = {0.f, 0.f};
    const v2f ONE = {1.f, 1.f};
    const v2f NTWO = {-2.f, -2.f};

    float* ob = out + (size_t)b * (S_LEN * HDIM) + 2 * l;

    // prefetch state
    float4 ycur, yn;
    const float* xb = PRE ? nullptr : (x + (size_t)b * (S_LEN * D_IN) + l);
    float xa = 0.f, xv_b = 0.f;
    if (PRE) { ycur = yxl[0]; yn = yxl[1]; }
    else     { xa = xb[0];    xv_b = xb[D_IN]; }

    // loop-invariant lane predicates (hoisted v_cmp -> s-pair masks)
    const bool lbit0 = (l & 1) != 0;
    const bool lbit1 = (l & 2) != 0;

    for (int t = 0; t < S_LEN; ++t) {
        // ---- projection partials (h-part; x-part precomputed on PRE path) ----
        v2f p01, p23;
        if (PRE) {
            p01 = fma2(splat2(h.y), wh1a, splat2(h.x) * wh0a);
            p23 = fma2(splat2(h.y), wh1b, splat2(h.x) * wh0b);
        } else {
            float xv = xa; xa = xv_b;
            int tn = t + 2; if (tn > S_LEN - 1) tn = S_LEN - 1;
            xv_b = xb[(size_t)tn * D_IN];
            p01 = fma2(splat2(h.y), wh1a, fma2(splat2(h.x), wh0a, fma2(splat2(xv), wxa, bna)));
            p23 = fma2(splat2(h.y), wh1b, fma2(splat2(h.x), wh0b, fma2(splat2(xv), wxb, bnb)));
        }

        float y0, y1, y2, y3;
        reduce4(p01.x, p01.y, p23.x, p23.y, y0, y1, y2, y3);

        // y sums arrive in SGPRs; combine with yx (VALU reads SGPR directly)
        float ya0, ya1, yb0, yb1;
        if (PRE) {
            ya0 = y0 + ycur.x;  ya1 = y1 + ycur.y;
            yb0 = y2 + ycur.z;  yb1 = y3 + ycur.w;
        } else {
            ya0 = y0; ya1 = y1; yb0 = y2; yb1 = y3;
        }

        // issue next-next yx LDS read (2-deep; only lgkm op in the loop)
        float4 yread2;
        if (PRE) yread2 = yxl[t + 2];

        // ---- Bloch vectors, LANE-PARALLEL over qubits (lane's qubit = l&3):
        // 2 rsq instructions instead of 8; identical per-qubit arithmetic ----
        float ysel_a = lbit0 ? ya1 : ya0;
        float ysel_b = lbit0 ? yb1 : yb0;
        float yq = lbit1 ? ysel_b : ysel_a;
        float y2s = yq * yq;
        float aq  = fmaf(yq, yq, 1.0f);
        float bq  = fmaf(y2s, y2s, 1.0f);
        float rr1 = rsq_f(aq);
        float rr2 = rsq_f(bq);
        float nxq = rr1 * rr2;
        float nyq = y2s * nxq;
        float nzq = -yq * rr1;

        // broadcast back to absolute qubit indices (quad_perm, full-rate)
        float nx0 = quad_bcast<0>(nxq), nx1 = quad_bcast<1>(nxq);
        float nx2 = quad_bcast<2>(nxq), nx3 = quad_bcast<3>(nxq);
        float ny0 = quad_bcast<0>(nyq), ny1 = quad_bcast<1>(nyq);
        float ny2 = quad_bcast<2>(nyq), ny3 = quad_bcast<3>(nyq);
        float nz0 = quad_bcast<0>(nzq), nz1 = quad_bcast<1>(nzq);
        float nz2 = quad_bcast<2>(nzq), nz3 = quad_bcast<3>(nzq);

        // ---- Pauli-string products (CNOT-ring conjugation) ----
        float nz01 = nz0 * nz1;
        float nz23 = nz2 * nz3;
        v2f TXa, TXb, TYa, TYb, TZa, TZb;
        TXa.x = nx0 * nx1;  TXa.y = nx1 * nx2;
        TXb.x = nx2 * nx3;  TXb.y = TXa.x * nx3;
        TZa.x = nz1 * nz23; TZa.y = nz01;
        TZb.x = nz01 * nz2; TZb.y = nz01 * nz23;
        TYa.x = (nx0 * ny1) * nz23;  TYa.y = (nz0 * ny1) * nx2;
        TYb.x = (nz01 * ny2) * nx3;  TYb.y = -(ny0 * ny1) * (nz2 * ny3);

        // ---- gate pre-activations for the lane's unit pair ----
        v2f pre[4];
#pragma unroll
        for (int g = 0; g < 4; ++g) {
            v2f za = fma2(UX[g][0], TXa, fma2(UY[g][0], TYa, UZ[g][0] * TZa));
            v2f zb = fma2(UX[g][1], TXb, fma2(UY[g][1], TYb, UZ[g][1] * TZb));
            v2f s = fma2(splat2(za.x), Wo[0], bo);
            s = fma2(splat2(za.y), Wo[1], s);
            s = fma2(splat2(zb.x), Wo[2], s);
            s = fma2(splat2(zb.y), Wo[3], s);
            pre[g] = s;
        }

        // ---- activations with merged reciprocals ----
        // f = sig(pre0), i = sig(pre1): share rcp of (1+ef)(1+ei)
        v2f ef = { __expf(-pre[0].x), __expf(-pre[0].y) };
        v2f ei = { __expf(-pre[1].x), __expf(-pre[1].y) };
        v2f af = ONE + ef, ai = ONE + ei;
        v2f Pfi = af * ai;
        v2f rfi = { rcp_f(Pfi.x), rcp_f(Pfi.y) };
        v2f fg = rfi * ai;
        v2f ig = rfi * af;
        // g = tanh(pre2) = 1 - 2/(1+e^{2*pre2}), o = sig(pre3): share rcp
        v2f eg = { __expf(2.0f * pre[2].x), __expf(2.0f * pre[2].y) };
        v2f eo = { __expf(-pre[3].x), __expf(-pre[3].y) };
        v2f ag = ONE + eg, ao = ONE + eo;
        v2f Pgo = ag * ao;
        v2f rgo = { rcp_f(Pgo.x), rcp_f(Pgo.y) };
        v2f gg = fma2(rgo * ao, NTWO, ONE);
        v2f og = rgo * ag;

        c = fma2(fg, c, ig * gg);
        h = og * tanh2(c);

        // rotate yx prefetch
        if (PRE) { ycur = yn; yn = yread2; }

        // store this step's unit pair (fire-and-forget, dwordx2)
        *reinterpret_cast<v2f*>(ob + (size_t)t * HDIM) = h;
    }

    // final h, c
    float* hT = out + (size_t)B_TOT * S_LEN * HDIM;
    float* cT = hT + (size_t)B_TOT * HDIM;
    *reinterpret_cast<v2f*>(hT + (size_t)b * HDIM + 2 * l) = h;
    *reinterpret_cast<v2f*>(cT + (size_t)b * HDIM + 2 * l) = c;
}

extern "C" void kernel_launch(void* const* d_in, const int* in_sizes, int n_in,
                              void* d_out, int out_size, void* d_ws, size_t ws_size,
                              hipStream_t stream) {
    const size_t yx_bytes = (size_t)B_TOT * S_LEN * 4 * sizeof(float);  // 2 MiB
    if (d_ws != nullptr && ws_size >= yx_bytes) {
        float4* yx = (float4*)d_ws;
        xproj_kernel<<<dim3(B_TOT * 16), dim3(64), 0, stream>>>(
            (const float*)d_in[0], (const float*)d_in[1], (const float*)d_in[2], yx);
        qlstm_kernel<true><<<dim3(B_TOT), dim3(64), 0, stream>>>(
            (const float*)d_in[0], (const float*)d_in[1], (const float*)d_in[2],
            (const float*)d_in[3], (const float*)d_in[4],
            (const float*)d_in[5], (const float*)d_in[6],
            (const float*)d_in[7], (const float*)d_in[8],
            (float*)d_out, yx);
    } else {
        qlstm_kernel<false><<<dim3(B_TOT), dim3(64), 0, stream>>>(
            (const float*)d_in[0], (const float*)d_in[1], (const float*)d_in[2],
            (const float*)d_in[3], (const float*)d_in[4],
            (const float*)d_in[5], (const float*)d_in[6],
            (const float*)d_in[7], (const float*)d_in[8],
            (float*)d_out, nullptr);
    }
}

// Round 7
// 211.422 us; speedup vs baseline: 1.0352x; 1.0352x over previous
//
#include <hip/hip_runtime.h>
#include <math.h>

#define B_TOT 512
#define S_LEN 256
#define D_IN  64
#define HDIM  128

typedef float v2f __attribute__((ext_vector_type(2)));

// ---- fast scalar ops (raw HW instructions; ~1-2 ulp, threshold is 1.5e-2) ----
__device__ __forceinline__ float rcp_f(float x) { return __builtin_amdgcn_rcpf(x); }
__device__ __forceinline__ float rsq_f(float x) { return __builtin_amdgcn_rsqf(x); }

__device__ __forceinline__ v2f fma2(v2f a, v2f b, v2f c) { return __builtin_elementwise_fma(a, b, c); }
__device__ __forceinline__ v2f splat2(float s) { v2f r = {s, s}; return r; }

// packed sigmoid / tanh (2 units at once)
__device__ __forceinline__ v2f sig2(v2f s) {
    v2f e = { __expf(-s.x), __expf(-s.y) };
    v2f ONE = {1.f, 1.f};
    v2f d = e + ONE;
    v2f r = { rcp_f(d.x), rcp_f(d.y) };
    return r;
}
__device__ __forceinline__ v2f tanh2(v2f s) {
    v2f t = s + s;
    v2f e = { __expf(t.x), __expf(t.y) };
    v2f ONE = {1.f, 1.f};
    v2f d = e + ONE;
    v2f r = { rcp_f(d.x), rcp_f(d.y) };
    v2f NTWO = {-2.f, -2.f};
    return fma2(r, NTWO, ONE);   // 1 - 2r
}

// ---------------------------------------------------------------------------
// Fused 4-value 64-lane all-reduce, one asm block, NO LDS.
// After 6 DPP stages lanes 48-63 hold the full total (proven rounds 4-6);
// v_readlane lane 63 -> SGPR: no LDS round-trip, no lgkmcnt wait.
// ---------------------------------------------------------------------------
__device__ __forceinline__ void reduce4(float p0, float p1, float p2, float p3,
                                        float& y0, float& y1, float& y2, float& y3) {
    asm volatile(
        "s_nop 1\n\t"
        "v_add_f32 %0, %0, %0 quad_perm:[1,0,3,2] row_mask:0xf bank_mask:0xf\n\t"
        "v_add_f32 %1, %1, %1 quad_perm:[1,0,3,2] row_mask:0xf bank_mask:0xf\n\t"
        "v_add_f32 %2, %2, %2 quad_perm:[1,0,3,2] row_mask:0xf bank_mask:0xf\n\t"
        "v_add_f32 %3, %3, %3 quad_perm:[1,0,3,2] row_mask:0xf bank_mask:0xf\n\t"
        "v_add_f32 %0, %0, %0 quad_perm:[2,3,0,1] row_mask:0xf bank_mask:0xf\n\t"
        "v_add_f32 %1, %1, %1 quad_perm:[2,3,0,1] row_mask:0xf bank_mask:0xf\n\t"
        "v_add_f32 %2, %2, %2 quad_perm:[2,3,0,1] row_mask:0xf bank_mask:0xf\n\t"
        "v_add_f32 %3, %3, %3 quad_perm:[2,3,0,1] row_mask:0xf bank_mask:0xf\n\t"
        "v_add_f32 %0, %0, %0 row_half_mirror row_mask:0xf bank_mask:0xf\n\t"
        "v_add_f32 %1, %1, %1 row_half_mirror row_mask:0xf bank_mask:0xf\n\t"
        "v_add_f32 %2, %2, %2 row_half_mirror row_mask:0xf bank_mask:0xf\n\t"
        "v_add_f32 %3, %3, %3 row_half_mirror row_mask:0xf bank_mask:0xf\n\t"
        "v_add_f32 %0, %0, %0 row_mirror row_mask:0xf bank_mask:0xf\n\t"
        "v_add_f32 %1, %1, %1 row_mirror row_mask:0xf bank_mask:0xf\n\t"
        "v_add_f32 %2, %2, %2 row_mirror row_mask:0xf bank_mask:0xf\n\t"
        "v_add_f32 %3, %3, %3 row_mirror row_mask:0xf bank_mask:0xf\n\t"
        "v_add_f32 %0, %0, %0 row_bcast:15 row_mask:0xf bank_mask:0xf bound_ctrl:0\n\t"
        "v_add_f32 %1, %1, %1 row_bcast:15 row_mask:0xf bank_mask:0xf bound_ctrl:0\n\t"
        "v_add_f32 %2, %2, %2 row_bcast:15 row_mask:0xf bank_mask:0xf bound_ctrl:0\n\t"
        "v_add_f32 %3, %3, %3 row_bcast:15 row_mask:0xf bank_mask:0xf bound_ctrl:0\n\t"
        "v_add_f32 %0, %0, %0 row_bcast:31 row_mask:0xf bank_mask:0xf bound_ctrl:0\n\t"
        "v_add_f32 %1, %1, %1 row_bcast:31 row_mask:0xf bank_mask:0xf bound_ctrl:0\n\t"
        "v_add_f32 %2, %2, %2 row_bcast:31 row_mask:0xf bank_mask:0xf bound_ctrl:0\n\t"
        "v_add_f32 %3, %3, %3 row_bcast:31 row_mask:0xf bank_mask:0xf bound_ctrl:0\n\t"
        "s_nop 1\n\t"
        "v_readlane_b32 %4, %0, 63\n\t"
        "v_readlane_b32 %5, %1, 63\n\t"
        "v_readlane_b32 %6, %2, 63\n\t"
        "v_readlane_b32 %7, %3, 63"
        : "+v"(p0), "+v"(p1), "+v"(p2), "+v"(p3),
          "=&s"(y0), "=&s"(y1), "=&s"(y2), "=&s"(y3));
}

// ---------------------------------------------------------------------------
// Phase 1: precompute yx[b][t][q] = b_in[q] + sum_d x[b,t,d] * Win[128+d][q].
// ---------------------------------------------------------------------------
__global__ void __launch_bounds__(64, 1) xproj_kernel(
    const float* __restrict__ x,    // (B,S,D)
    const float* __restrict__ Win,  // (192,4)
    const float* __restrict__ bin,  // (4)
    float4* __restrict__ yx)        // (B,S) float4
{
    const int l  = threadIdx.x;
    const int b  = blockIdx.x >> 4;
    const int t0 = (blockIdx.x & 15) << 4;

    const float4 wx = reinterpret_cast<const float4*>(Win)[128 + l];
    const float4 bn = *reinterpret_cast<const float4*>(bin);

    const float* xp = x + ((size_t)b * S_LEN + t0) * D_IN + l;
    float4* yp = yx + (size_t)b * S_LEN + t0;

#pragma unroll 4
    for (int tt = 0; tt < 16; ++tt) {
        float xv = xp[(size_t)tt * D_IN];
        float y0, y1, y2, y3;
        reduce4(xv * wx.x, xv * wx.y, xv * wx.z, xv * wx.w, y0, y1, y2, y3);
        if (l == 0)
            yp[tt] = make_float4(y0 + bn.x, y1 + bn.y, y2 + bn.z, y3 + bn.w);
    }
}

// ---------------------------------------------------------------------------
// Phase 2: serial recurrence. 256 blocks x 128 threads; each block carries TWO
// fully independent waves (wave w = batch 2*blockIdx+w, no barrier, private
// LDS slice). Rationale: the SPI places the 2 waves of one workgroup on
// DIFFERENT SIMDs, which the 512x1-wave launch cannot guarantee -- this
// removes possible same-SIMD issue contention between the 2 waves/CU.
// Per-wave step math is IDENTICAL to the proven round-5 kernel.
// ---------------------------------------------------------------------------
template<bool PRE>
__global__ void __launch_bounds__(128, 1) qlstm_kernel(
    const float* __restrict__ x,    // (B,S,D)
    const float* __restrict__ Win,  // (192,4)
    const float* __restrict__ bin,  // (4)
    const float* __restrict__ Wout, // (4,128)
    const float* __restrict__ bout, // (128)
    const float* __restrict__ wf,   // (1,3,4)
    const float* __restrict__ wi,
    const float* __restrict__ wu,
    const float* __restrict__ wo,
    float* __restrict__ out,        // outs (B,S,128) ++ hT (B,128) ++ cT (B,128)
    const float4* __restrict__ yx)  // (B,S) precomputed x-projection (PRE only)
{
    const int tid = threadIdx.x;    // 0..127
    const int w = tid >> 6;         // wave id (independent batch)
    const int l = tid & 63;         // lane 0..63
    const int b = blockIdx.x * 2 + w;

    __shared__ float4 yxl[2][S_LEN + 2];   // per-wave staged x-projection

    // ---- h-part W_in rows for this lane's two units (packed over q-pairs) ----
    const float4* W4 = reinterpret_cast<const float4*>(Win);
    const float4 r0 = W4[2 * l];
    const float4 r1 = W4[2 * l + 1];
    const v2f wh0a = {r0.x, r0.y}, wh0b = {r0.z, r0.w};
    const v2f wh1a = {r1.x, r1.y}, wh1b = {r1.z, r1.w};

    // x-part (fallback path only): lane owns feature l; bias folded /64
    v2f wxa = {0.f, 0.f}, wxb = {0.f, 0.f}, bna = {0.f, 0.f}, bnb = {0.f, 0.f};
    if (!PRE) {
        const float4 rx = W4[128 + l];
        wxa.x = rx.x; wxa.y = rx.y; wxb.x = rx.z; wxb.y = rx.w;
        const float4 bn = *reinterpret_cast<const float4*>(bin);
        bna.x = bn.x * 0.015625f; bna.y = bn.y * 0.015625f;
        bnb.x = bn.z * 0.015625f; bnb.y = bn.w * 0.015625f;
    } else {
        // stage this wave's batch row into its private LDS slice (no barrier:
        // each wave reads only what it wrote)
        const float4* yxg = yx + (size_t)b * S_LEN;
#pragma unroll
        for (int k = 0; k < 4; ++k)
            yxl[w][(k << 6) + l] = yxg[(k << 6) + l];
    }

    // W_out for units 2l, 2l+1 (packed over the unit pair)
    v2f Wo[4];
#pragma unroll
    for (int q = 0; q < 4; ++q) {
        Wo[q].x = Wout[q * HDIM + 2 * l];
        Wo[q].y = Wout[q * HDIM + 2 * l + 1];
    }
    const v2f bo = {bout[2 * l], bout[2 * l + 1]};

    // measurement coefficients, packed over q-pairs: [g][0]=(q0,q1) [g][1]=(q2,q3)
    v2f UX[4][2], UY[4][2], UZ[4][2];
    {
        const float* wg[4] = {wf, wi, wu, wo};
#pragma unroll
        for (int g = 0; g < 4; ++g) {
#pragma unroll
            for (int p = 0; p < 2; ++p) {
#pragma unroll
                for (int e = 0; e < 2; ++e) {
                    int q = 2 * p + e;
                    float a  = wg[g][q];
                    float be = wg[g][4 + q];
                    float sa = sinf(a),  ca = cosf(a);
                    float sb = sinf(be), cb = cosf(be);
                    UX[g][p][e] = -sb;
                    UY[g][p][e] = cb * sa;
                    UZ[g][p][e] = cb * ca;
                }
            }
        }
    }

    v2f h = {0.f, 0.f}, c = {0.f, 0.f};
    const v2f ONE = {1.f, 1.f};

    float* ob = out + (size_t)b * (S_LEN * HDIM) + 2 * l;

    // prefetch state
    float4 ycur, yn;
    const float* xb = PRE ? nullptr : (x + (size_t)b * (S_LEN * D_IN) + l);
    float xa = 0.f, xv_b = 0.f;
    if (PRE) { ycur = yxl[w][0]; yn = yxl[w][1]; }
    else     { xa = xb[0];       xv_b = xb[D_IN]; }

    for (int t = 0; t < S_LEN; ++t) {
        // ---- projection partials (h-part; x-part precomputed on PRE path) ----
        v2f p01, p23;
        if (PRE) {
            p01 = fma2(splat2(h.y), wh1a, splat2(h.x) * wh0a);
            p23 = fma2(splat2(h.y), wh1b, splat2(h.x) * wh0b);
        } else {
            float xv = xa; xa = xv_b;
            int tn = t + 2; if (tn > S_LEN - 1) tn = S_LEN - 1;
            xv_b = xb[(size_t)tn * D_IN];
            p01 = fma2(splat2(h.y), wh1a, fma2(splat2(h.x), wh0a, fma2(splat2(xv), wxa, bna)));
            p23 = fma2(splat2(h.y), wh1b, fma2(splat2(h.x), wh0b, fma2(splat2(xv), wxb, bnb)));
        }

        float y0, y1, y2, y3;
        reduce4(p01.x, p01.y, p23.x, p23.y, y0, y1, y2, y3);

        // y sums arrive in SGPRs; combine with yx (VALU reads SGPR directly)
        v2f yA, yB;
        if (PRE) {
            yA.x = y0 + ycur.x;  yA.y = y1 + ycur.y;
            yB.x = y2 + ycur.z;  yB.y = y3 + ycur.w;
        } else {
            yA.x = y0; yA.y = y1; yB.x = y2; yB.y = y3;
        }

        // issue next-next yx LDS read (2-deep; only lgkm op in the loop)
        float4 yread2;
        if (PRE) yread2 = yxl[w][t + 2];

        // ---- Bloch vectors, packed over q-pairs (arctans cancel analytically) ----
        v2f qA = yA * yA,  qB = yB * yB;
        v2f aA = fma2(yA, yA, ONE), aB = fma2(yB, yB, ONE);
        v2f bA = fma2(qA, qA, ONE), bB = fma2(qB, qB, ONE);
        v2f r1A = { rsq_f(aA.x), rsq_f(aA.y) };
        v2f r1B = { rsq_f(aB.x), rsq_f(aB.y) };
        v2f r2A = { rsq_f(bA.x), rsq_f(bA.y) };
        v2f r2B = { rsq_f(bB.x), rsq_f(bB.y) };
        v2f nxA = r1A * r2A, nxB = r1B * r2B;
        v2f nyA = qA * nxA,  nyB = qB * nxB;
        v2f nzA = -(yA * r1A), nzB = -(yB * r1B);
        float nx0 = nxA.x, nx1 = nxA.y, nx2 = nxB.x, nx3 = nxB.y;
        float ny0 = nyA.x, ny1 = nyA.y, ny2 = nyB.x, ny3 = nyB.y;
        float nz0 = nzA.x, nz1 = nzA.y, nz2 = nzB.x, nz3 = nzB.y;

        // ---- Pauli-string products (CNOT-ring conjugation) ----
        float nz01 = nz0 * nz1;
        float nz23 = nz2 * nz3;
        v2f TXa, TXb, TYa, TYb, TZa, TZb;
        TXa.x = nx0 * nx1;  TXa.y = nx1 * nx2;
        TXb.x = nx2 * nx3;  TXb.y = TXa.x * nx3;
        TZa.x = nz1 * nz23; TZa.y = nz01;
        TZb.x = nz01 * nz2; TZb.y = nz01 * nz23;
        TYa.x = (nx0 * ny1) * nz23;  TYa.y = (nz0 * ny1) * nx2;
        TYb.x = (nz01 * ny2) * nx3;  TYb.y = -(ny0 * ny1) * (nz2 * ny3);

        // ---- gate pre-activations for the lane's unit pair ----
        v2f pre[4];
#pragma unroll
        for (int g = 0; g < 4; ++g) {
            v2f za = fma2(UX[g][0], TXa, fma2(UY[g][0], TYa, UZ[g][0] * TZa));
            v2f zb = fma2(UX[g][1], TXb, fma2(UY[g][1], TYb, UZ[g][1] * TZb));
            v2f s = fma2(splat2(za.x), Wo[0], bo);
            s = fma2(splat2(za.y), Wo[1], s);
            s = fma2(splat2(zb.x), Wo[2], s);
            s = fma2(splat2(zb.y), Wo[3], s);
            pre[g] = s;
        }

        v2f fg = sig2(pre[0]);
        v2f ig = sig2(pre[1]);
        v2f gg = tanh2(pre[2]);
        v2f og = sig2(pre[3]);
        c = fma2(fg, c, ig * gg);
        h = og * tanh2(c);

        // rotate yx prefetch
        if (PRE) { ycur = yn; yn = yread2; }

        // store this step's unit pair (fire-and-forget, dwordx2)
        *reinterpret_cast<v2f*>(ob + (size_t)t * HDIM) = h;
    }

    // final h, c
    float* hT = out + (size_t)B_TOT * S_LEN * HDIM;
    float* cT = hT + (size_t)B_TOT * HDIM;
    *reinterpret_cast<v2f*>(hT + (size_t)b * HDIM + 2 * l) = h;
    *reinterpret_cast<v2f*>(cT + (size_t)b * HDIM + 2 * l) = c;
}

extern "C" void kernel_launch(void* const* d_in, const int* in_sizes, int n_in,
                              void* d_out, int out_size, void* d_ws, size_t ws_size,
                              hipStream_t stream) {
    const size_t yx_bytes = (size_t)B_TOT * S_LEN * 4 * sizeof(float);  // 2 MiB
    if (d_ws != nullptr && ws_size >= yx_bytes) {
        float4* yx = (float4*)d_ws;
        xproj_kernel<<<dim3(B_TOT * 16), dim3(64), 0, stream>>>(
            (const float*)d_in[0], (const float*)d_in[1], (const float*)d_in[2], yx);
        qlstm_kernel<true><<<dim3(B_TOT / 2), dim3(128), 0, stream>>>(
            (const float*)d_in[0], (const float*)d_in[1], (const float*)d_in[2],
            (const float*)d_in[3], (const float*)d_in[4],
            (const float*)d_in[5], (const float*)d_in[6],
            (const float*)d_in[7], (const float*)d_in[8],
            (float*)d_out, yx);
    } else {
        qlstm_kernel<false><<<dim3(B_TOT / 2), dim3(128), 0, stream>>>(
            (const float*)d_in[0], (const float*)d_in[1], (const float*)d_in[2],
            (const float*)d_in[3], (const float*)d_in[4],
            (const float*)d_in[5], (const float*)d_in[6],
            (const float*)d_in[7], (const float*)d_in[8],
            (float*)d_out, nullptr);
    }
}